// Round 5
// baseline (33.615 us; speedup 1.0000x reference)
//
#include <hip/hip_runtime.h>

#define NBOX 8192
#define MAXDET 100
#define SCORE_T 0.05f
#define NMS_T 0.5f
#define CAP 1024
#define KTGT 128
#define BT2 512

__device__ __forceinline__ float iou_fn(float x1, float y1, float x2, float y2, float area,
                                        float bx1, float by1, float bx2, float by2, float barea) {
    float iw = fminf(x2, bx2) - fmaxf(x1, bx1);
    float ih = fminf(y2, by2) - fmaxf(y1, by1);
    iw = fmaxf(iw, 0.0f);
    ih = fmaxf(ih, 0.0f);
    float inter = iw * ih;
    return inter / fmaxf(area + barea - inter, 1e-8f);
}

__device__ __forceinline__ void bins_of(unsigned k, int& b1, int& b2) {
    float s = __uint_as_float(k & 0x7FFFFFFFu);
    b1 = (int)(s * 256.0f); if (b1 > 255) b1 = 255;
    b2 = (int)(s * 65536.0f) & 255;
}

// ---- Kernel 1 (32 blocks): keys + per-block transposed histograms ----
__global__ __launch_bounds__(256) void score_hist_kernel(
    const float* __restrict__ cls, unsigned* __restrict__ keys,
    unsigned* __restrict__ histT) {
    __shared__ unsigned s_h[256];
    const int t = threadIdx.x, blk = blockIdx.x;
    s_h[t] = 0u;
    const int i = blk * 256 + t;
    const float4 c0 = *reinterpret_cast<const float4*>(cls + i * 8);
    const float4 c1 = *reinterpret_cast<const float4*>(cls + i * 8 + 4);
    float s = fmaxf(fmaxf(fmaxf(c0.x, c1.x), fmaxf(c0.y, c1.y)),
                    fmaxf(fmaxf(c0.z, c1.z), fmaxf(c0.w, c1.w)));
    unsigned u = __float_as_uint(s);
    unsigned key = (u >> 31) ? ~u : (u | 0x80000000u);
    key = (s > SCORE_T) ? key : 0u;
    keys[i] = key;
    __syncthreads();
    if (key) { int b1, b2; bins_of(key, b1, b2); atomicAdd(&s_h[b1], 1u); }
    __syncthreads();
    histT[t * 32 + blk] = s_h[t];   // bin-major: kernel2 thread t sums 32 contiguous
}

// ---- Kernel 2 (1 block): select band, sort, exact greedy NMS, output ----
__global__ __launch_bounds__(BT2) void select_nms_kernel(
    const float* __restrict__ boxes, const float* __restrict__ dims,
    const float* __restrict__ cls, const unsigned* __restrict__ keys,
    const unsigned* __restrict__ histT, float* __restrict__ out) {
    __shared__ unsigned s_key[NBOX];              // 32KB
    __shared__ unsigned s_hist[256];
    __shared__ unsigned long long s_sel[CAP];     // 8KB
    __shared__ unsigned long long s_srt[CAP];     // 8KB
    __shared__ unsigned short s_srtpos[CAP];      // 2KB
    __shared__ float4 s_cb[CAP];                  // 16KB
    __shared__ float s_kx1[MAXDET], s_ky1[MAXDET], s_kx2[MAXDET], s_ky2[MAXDET];
    __shared__ float s_karea[MAXDET], s_kscore[MAXDET];
    __shared__ int s_ksel[MAXDET];
    __shared__ float s_bx1[128], s_by1[128], s_bx2[128], s_by2[128], s_bar[128];
    __shared__ int s_kc, s_cnt, s_B1, s_B2, s_state, s_refKrem;
    __shared__ unsigned long long s_alive0;

    const int tid = threadIdx.x;
    const int lane = tid & 63;
    const int wid = tid >> 6;

    // merge per-block histograms + load keys to LDS
    if (tid < 256) {
        const uint4* hp = reinterpret_cast<const uint4*>(histT) + tid * 8;
        unsigned sum = 0u;
#pragma unroll
        for (int j = 0; j < 8; ++j) { uint4 v = hp[j]; sum += v.x + v.y + v.z + v.w; }
        s_hist[tid] = sum;
    }
    {
        const uint4* kp = reinterpret_cast<const uint4*>(keys);
        uint4* sk = reinterpret_cast<uint4*>(s_key);
#pragma unroll
        for (int j = 0; j < NBOX / 4 / BT2; ++j) sk[tid + j * BT2] = kp[tid + j * BT2];
    }
    if (tid == 0) { s_kc = 0; s_cnt = 0; }
    __syncthreads();

    int U1 = 256, U2 = 0;   // exclusive lexicographic upper bound (bin1,bin2)
    while (true) {
        // ---- wave-0 shfl-only suffix scan + threshold pick ----
        if (wid == 0) {
            unsigned c0 = s_hist[lane * 4 + 0], c1s = s_hist[lane * 4 + 1];
            unsigned c2 = s_hist[lane * 4 + 2], c3 = s_hist[lane * 4 + 3];
            unsigned t3 = c3, t2 = c2 + t3, t1 = c1s + t2, t0 = c0 + t1;
            unsigned acc = t0;
#pragma unroll
            for (int d = 1; d < 64; d <<= 1) {
                unsigned o = __shfl_down(acc, d);
                if (lane + d < 64) acc += o;
            }
            unsigned excl = acc - t0;
            unsigned totalRem = __shfl(acc, 0);
            if (lane == 0) s_state = (totalRem == 0u) ? 2 : 0;
            if (totalRem != 0u) {
                unsigned Kt = totalRem < (unsigned)KTGT ? totalRem : (unsigned)KTGT;
                unsigned incq[4] = { excl + t0, excl + t1, excl + t2, excl + t3 };
                unsigned abvq[4] = { excl + t1, excl + t2, excl + t3, excl };
#pragma unroll
                for (int q = 0; q < 4; ++q) {
                    if (incq[q] >= Kt && abvq[q] < Kt) {
                        s_B1 = lane * 4 + q; s_B2 = 0;
                        if (incq[q] > CAP) { s_state = 1; s_refKrem = (int)(Kt - abvq[q]); }
                    }
                }
            }
        }
        __syncthreads();
        const int st = s_state;
        if (st == 2) break;
        const int B1 = s_B1;
        if (st == 1) {
            // ---- rare refine on 2nd-level bins (unreachable for this input) ----
            if (tid < 256) s_hist[tid] = 0u;
            __syncthreads();
            for (int j = 0; j < NBOX / BT2; ++j) {
                unsigned k = s_key[tid + j * BT2];
                if (k) {
                    int b1, b2; bins_of(k, b1, b2);
                    if ((b1 < U1 || (b1 == U1 && b2 < U2)) && b1 == B1)
                        atomicAdd(&s_hist[b2], 1u);
                }
            }
            __syncthreads();
            if (wid == 0) {
                unsigned c0 = s_hist[lane * 4 + 0], c1s = s_hist[lane * 4 + 1];
                unsigned c2 = s_hist[lane * 4 + 2], c3 = s_hist[lane * 4 + 3];
                unsigned t3 = c3, t2 = c2 + t3, t1 = c1s + t2, t0 = c0 + t1;
                unsigned acc = t0;
#pragma unroll
                for (int d = 1; d < 64; d <<= 1) {
                    unsigned o = __shfl_down(acc, d);
                    if (lane + d < 64) acc += o;
                }
                unsigned excl = acc - t0;
                unsigned Krem = (unsigned)s_refKrem;
                unsigned incq[4] = { excl + t0, excl + t1, excl + t2, excl + t3 };
                unsigned abvq[4] = { excl + t1, excl + t2, excl + t3, excl };
#pragma unroll
                for (int q = 0; q < 4; ++q)
                    if (incq[q] >= Krem && abvq[q] < Krem) s_B2 = lane * 4 + q;
            }
            __syncthreads();
        }
        const int B2 = s_B2;

        // ---- compact band [(B1,B2), U) ----
        for (int j = 0; j < NBOX / BT2; ++j) {
            int i = tid + j * BT2;
            unsigned k = s_key[i];
            if (k) {
                int b1, b2; bins_of(k, b1, b2);
                bool inr = (b1 < U1) || (b1 == U1 && b2 < U2);
                bool sel = inr && ((b1 > B1) || (b1 == B1 && b2 >= B2));
                if (sel) {
                    int pos = atomicAdd(&s_cnt, 1);
                    if (pos < CAP)
                        s_sel[pos] = (((unsigned long long)k) << 13) | (unsigned)(NBOX - 1 - i);
                }
            }
        }
        __syncthreads();
        const int sc = s_cnt < CAP ? s_cnt : CAP;

        // ---- box prefetch + rank-sort (keys distinct; broadcast LDS reads) ----
        if (tid < sc) {
            unsigned long long mine = s_sel[tid];
            int bidx = NBOX - 1 - (int)(mine & 8191ull);
            float4 preb = *reinterpret_cast<const float4*>(boxes + bidx * 12);
            int rank = 0;
            for (int j = 0; j < sc; ++j) rank += (s_sel[j] > mine) ? 1 : 0;
            s_srt[rank] = mine;
            s_srtpos[rank] = (unsigned short)tid;
            s_cb[tid] = preb;
        }
        __syncthreads();

        // ---- 2-wave cooperative greedy NMS, groups of 128 (exact) ----
        for (int base = 0; base < sc && s_kc < MAXDET; base += 128) {
            const int kc0 = s_kc;
            float x1 = 0.f, y1 = 0.f, x2 = 0.f, y2 = 0.f, area = 0.f, sscore = 0.f;
            int sidx = 0; bool have = false;
            if (wid < 2) {
                int p = base + wid * 64 + lane;
                have = p < sc;
                unsigned long long v = have ? s_srt[p] : 0ull;
                int cp = have ? (int)s_srtpos[p] : 0;
                sidx = NBOX - 1 - (int)(v & 8191ull);
                sscore = __uint_as_float(((unsigned)(v >> 13)) & 0x7FFFFFFFu);
                float4 b = s_cb[cp];
                if (have) { x1 = b.x; y1 = b.y; x2 = b.z; y2 = b.w; area = (x2 - x1) * (y2 - y1); }
                int sl = wid * 64 + lane;
                s_bx1[sl] = x1; s_by1[sl] = y1; s_bx2[sl] = x2; s_by2[sl] = y2; s_bar[sl] = area;
            }
            __syncthreads();
            if (wid == 0) {
                bool cand = have;
                for (int k = 0; k < kc0; ++k) {
                    float iou = iou_fn(x1, y1, x2, y2, area,
                                       s_kx1[k], s_ky1[k], s_kx2[k], s_ky2[k], s_karea[k]);
                    cand = cand && !(iou > NMS_T);
                }
                unsigned long long m = 0ull;
#pragma unroll 4
                for (int j = 0; j < 64; ++j) {
                    float iou = iou_fn(x1, y1, x2, y2, area,
                                       s_bx1[j], s_by1[j], s_bx2[j], s_by2[j], s_bar[j]);
                    if ((iou > NMS_T) && (j < lane)) m |= (1ull << j);
                }
                unsigned long long alive = __ballot(cand);
                unsigned long long conf = __ballot((m & alive) != 0ull) & alive;
                while (conf) {
                    int i = (int)__builtin_ctzll(conf);
                    bool deadI = (lane == i) && ((m & alive) != 0ull);
                    unsigned long long d = __ballot(deadI);
                    alive &= ~d; conf &= ~(d | (1ull << i));
                }
                int rank = (int)__popcll(alive & ((1ull << lane) - 1ull));
                int slot = kc0 + rank;
                if (((alive >> lane) & 1ull) && slot < MAXDET) {
                    s_kx1[slot] = x1; s_ky1[slot] = y1; s_kx2[slot] = x2; s_ky2[slot] = y2;
                    s_karea[slot] = area; s_kscore[slot] = sscore; s_ksel[slot] = sidx;
                }
                if (lane == 0) s_alive0 = alive;
            }
            unsigned long long m_low = 0ull, m_high = 0ull;
            bool cand1 = have;
            if (wid == 1) {
                // concurrent with wave-0's resolve: masks vs kept list & vs candidates
                for (int k = 0; k < kc0; ++k) {
                    float iou = iou_fn(x1, y1, x2, y2, area,
                                       s_kx1[k], s_ky1[k], s_kx2[k], s_ky2[k], s_karea[k]);
                    cand1 = cand1 && !(iou > NMS_T);
                }
#pragma unroll 4
                for (int j = 0; j < 64; ++j) {
                    float iou = iou_fn(x1, y1, x2, y2, area,
                                       s_bx1[j], s_by1[j], s_bx2[j], s_by2[j], s_bar[j]);
                    if (iou > NMS_T) m_low |= (1ull << j);
                }
#pragma unroll 4
                for (int j = 0; j < 64; ++j) {
                    float iou = iou_fn(x1, y1, x2, y2, area,
                                       s_bx1[64 + j], s_by1[64 + j], s_bx2[64 + j], s_by2[64 + j], s_bar[64 + j]);
                    if ((iou > NMS_T) && (j < lane)) m_high |= (1ull << j);
                }
            }
            __syncthreads();
            if (wid == 1) {
                unsigned long long alive0 = s_alive0;
                int popc0 = (int)__popcll(alive0);
                bool cand = cand1 && ((m_low & alive0) == 0ull);
                unsigned long long alive = __ballot(cand);
                unsigned long long conf = __ballot((m_high & alive) != 0ull) & alive;
                while (conf) {
                    int i = (int)__builtin_ctzll(conf);
                    bool deadI = (lane == i) && ((m_high & alive) != 0ull);
                    unsigned long long d = __ballot(deadI);
                    alive &= ~d; conf &= ~(d | (1ull << i));
                }
                int rank = (int)__popcll(alive & ((1ull << lane) - 1ull));
                int slot = kc0 + popc0 + rank;
                if (((alive >> lane) & 1ull) && slot < MAXDET) {
                    s_kx1[slot] = x1; s_ky1[slot] = y1; s_kx2[slot] = x2; s_ky2[slot] = y2;
                    s_karea[slot] = area; s_kscore[slot] = sscore; s_ksel[slot] = sidx;
                }
                if (lane == 0) {
                    int nk = kc0 + popc0 + (int)__popcll(alive);
                    s_kc = nk > MAXDET ? MAXDET : nk;
                }
            }
            __syncthreads();
        }
        if (s_kc >= MAXDET) break;
        // ---- restart with next band (rare): rebuild bounded histogram ----
        U1 = B1; U2 = B2;
        if (tid < 256) s_hist[tid] = 0u;
        if (tid == 0) s_cnt = 0;
        __syncthreads();
        for (int j = 0; j < NBOX / BT2; ++j) {
            unsigned k = s_key[tid + j * BT2];
            if (k) {
                int b1, b2; bins_of(k, b1, b2);
                if (b1 < U1 || (b1 == U1 && b2 < U2)) atomicAdd(&s_hist[b1], 1u);
            }
        }
        __syncthreads();
    }
    __syncthreads();

    // ---- output: 100 slots ----
    if (tid < MAXDET) {
        const int kc = s_kc;
        float* ob = out;                 // (100,12)
        float* od = out + MAXDET * 12;   // (100,3)
        float* os = out + MAXDET * 15;   // (100,)
        float* ol = out + MAXDET * 16;   // (100,) labels
        float* oo = out + MAXDET * 17;   // (100,) orient
        float4* obr = reinterpret_cast<float4*>(ob + tid * 12);
        if (tid < kc) {
            int sel = s_ksel[tid];
            const float4* br = reinterpret_cast<const float4*>(boxes + sel * 12);
            obr[0] = br[0]; obr[1] = br[1]; obr[2] = br[2];
            od[tid * 3 + 0] = dims[sel * 3 + 0];
            od[tid * 3 + 1] = dims[sel * 3 + 1];
            od[tid * 3 + 2] = dims[sel * 3 + 2];
            os[tid] = s_kscore[tid];
            ol[tid] = 0.0f;
            const float4 c0 = *reinterpret_cast<const float4*>(cls + sel * 8);
            const float4 c1 = *reinterpret_cast<const float4*>(cls + sel * 8 + 4);
            float m0 = fmaxf(c0.x, c1.x);
            float m1 = fmaxf(c0.y, c1.y);
            float m2 = fmaxf(c0.z, c1.z);
            float m3 = fmaxf(c0.w, c1.w);
            int o = 0; float best = m0;
            if (m1 > best) { best = m1; o = 1; }
            if (m2 > best) { best = m2; o = 2; }
            if (m3 > best) { best = m3; o = 3; }
            oo[tid] = (float)o;
        } else {
            const float4 neg1 = make_float4(-1.f, -1.f, -1.f, -1.f);
            obr[0] = neg1; obr[1] = neg1; obr[2] = neg1;
            od[tid * 3 + 0] = -1.0f; od[tid * 3 + 1] = -1.0f; od[tid * 3 + 2] = -1.0f;
            os[tid] = -1.0f; ol[tid] = -1.0f; oo[tid] = -1.0f;
        }
    }
}

extern "C" void kernel_launch(void* const* d_in, const int* in_sizes, int n_in,
                              void* d_out, int out_size, void* d_ws, size_t ws_size,
                              hipStream_t stream) {
    const float* boxes = (const float*)d_in[0];
    const float* dims  = (const float*)d_in[1];
    const float* cls   = (const float*)d_in[2];
    float* out = (float*)d_out;
    unsigned* keys  = (unsigned*)d_ws;             // 8192 u32
    unsigned* histT = (unsigned*)d_ws + NBOX;      // 256*32 u32
    (void)in_sizes; (void)n_in; (void)out_size; (void)ws_size;
    score_hist_kernel<<<32, 256, 0, stream>>>(cls, keys, histT);
    select_nms_kernel<<<1, BT2, 0, stream>>>(boxes, dims, cls, keys, histT, out);
}

// Round 6
// 31.687 us; speedup vs baseline: 1.0608x; 1.0608x over previous
//
#include <hip/hip_runtime.h>

#define NBOX 8192
#define MAXDET 100
#define SCORE_T 0.05f
#define NMS_T 0.5f
#define CAP 1024
#define KTGT 128
#define BT2 256

typedef unsigned long long u64;

// ws layout (bytes): [0] u32 counter | [1024] u32 keys[8192] | [33792] u64 kidx[1024] | [41984] float4 fb0[1024]
#define WS_KEYS 1024
#define WS_KIDX 33792
#define WS_FB0  41984

__device__ __forceinline__ float iou_fn(float x1, float y1, float x2, float y2, float area,
                                        float bx1, float by1, float bx2, float by2, float barea) {
    float iw = fminf(x2, bx2) - fmaxf(x1, bx1);
    float ih = fminf(y2, by2) - fmaxf(y1, by1);
    iw = fmaxf(iw, 0.0f);
    ih = fmaxf(ih, 0.0f);
    float inter = iw * ih;
    return inter / fmaxf(area + barea - inter, 1e-8f);
}

__device__ __forceinline__ void bins_of(unsigned k, int& b1, int& b2) {
    float s = __uint_as_float(k & 0x7FFFFFFFu);
    b1 = (int)(s * 256.0f); if (b1 > 255) b1 = 255;
    b2 = (int)(s * 65536.0f) & 255;
}

// ---- Kernel 1 (64 blocks): keys + direct push of top-bin candidates ----
__global__ __launch_bounds__(128) void score_push_kernel(
    const float* __restrict__ boxes, const float* __restrict__ cls,
    unsigned* __restrict__ keys, unsigned* __restrict__ cnt,
    u64* __restrict__ kidx, float4* __restrict__ fb0) {
    const int i = blockIdx.x * 128 + threadIdx.x;
    const float4 c0 = *reinterpret_cast<const float4*>(cls + i * 8);
    const float4 c1 = *reinterpret_cast<const float4*>(cls + i * 8 + 4);
    float s = fmaxf(fmaxf(fmaxf(c0.x, c1.x), fmaxf(c0.y, c1.y)),
                    fmaxf(fmaxf(c0.z, c1.z), fmaxf(c0.w, c1.w)));
    unsigned u = __float_as_uint(s);
    unsigned key = (u >> 31) ? ~u : (u | 0x80000000u);
    key = (s > SCORE_T) ? key : 0u;
    keys[i] = key;
    int b1 = (int)(s * 256.0f); if (b1 > 255) b1 = 255;
    if (key && b1 == 255) {
        unsigned pos = atomicAdd(cnt, 1u);
        if (pos < CAP) {
            kidx[pos] = (((u64)key) << 13) | (unsigned)(NBOX - 1 - i);
            fb0[pos] = *reinterpret_cast<const float4*>(boxes + i * 12);
        }
    }
}

// ---- Kernel 2 (1 block, 256 threads): sort + exact greedy NMS + output ----
__global__ __launch_bounds__(BT2) void select_nms_kernel(
    const float* __restrict__ boxes, const float* __restrict__ dims,
    const float* __restrict__ cls, const unsigned* __restrict__ keysG,
    const unsigned* __restrict__ cntG, const u64* __restrict__ kidxG,
    const float4* __restrict__ fb0G, float* __restrict__ out) {
    __shared__ unsigned s_key[NBOX];              // 32KB (fallback only)
    __shared__ unsigned s_hist[256];
    __shared__ u64 s_sel[CAP];                    // 8KB
    __shared__ u64 s_srt[CAP];                    // 8KB
    __shared__ unsigned short s_srtpos[CAP];      // 2KB
    __shared__ float4 s_cb[CAP];                  // 16KB
    __shared__ float s_kx1[MAXDET], s_ky1[MAXDET], s_kx2[MAXDET], s_ky2[MAXDET];
    __shared__ float s_karea[MAXDET], s_kscore[MAXDET];
    __shared__ int s_ksel[MAXDET];
    __shared__ float s_bx1[128], s_by1[128], s_bx2[128], s_by2[128], s_bar[128];
    __shared__ int s_kc, s_cnt, s_B1, s_B2, s_state, s_refKrem;
    __shared__ u64 s_alive0;

    const int tid = threadIdx.x;
    const int lane = tid & 63;
    const int wid = tid >> 6;

    // exact greedy NMS over s_srt[0..scN), 2-wave cooperative, groups of 128
    auto nms_groups = [&](int scN) {
        for (int base = 0; base < scN && s_kc < MAXDET; base += 128) {
            const int kc0 = s_kc;
            float x1 = 0.f, y1 = 0.f, x2 = 0.f, y2 = 0.f, area = 0.f, sscore = 0.f;
            int sidx = 0; bool have = false;
            if (wid < 2) {
                int p = base + wid * 64 + lane;
                have = p < scN;
                u64 v = have ? s_srt[p] : 0ull;
                int cp = have ? (int)s_srtpos[p] : 0;
                sidx = NBOX - 1 - (int)(v & 8191ull);
                sscore = __uint_as_float(((unsigned)(v >> 13)) & 0x7FFFFFFFu);
                float4 b = s_cb[cp];
                if (have) { x1 = b.x; y1 = b.y; x2 = b.z; y2 = b.w; area = (x2 - x1) * (y2 - y1); }
                int sl = wid * 64 + lane;
                s_bx1[sl] = x1; s_by1[sl] = y1; s_bx2[sl] = x2; s_by2[sl] = y2; s_bar[sl] = area;
            }
            __syncthreads();
            if (wid == 0) {
                bool cand = have;
                for (int k = 0; k < kc0; ++k) {
                    float iou = iou_fn(x1, y1, x2, y2, area,
                                       s_kx1[k], s_ky1[k], s_kx2[k], s_ky2[k], s_karea[k]);
                    cand = cand && !(iou > NMS_T);
                }
                u64 m = 0ull;
#pragma unroll 4
                for (int j = 0; j < 64; ++j) {
                    float iou = iou_fn(x1, y1, x2, y2, area,
                                       s_bx1[j], s_by1[j], s_bx2[j], s_by2[j], s_bar[j]);
                    if ((iou > NMS_T) && (j < lane)) m |= (1ull << j);
                }
                u64 alive = __ballot(cand);
                u64 conf = __ballot((m & alive) != 0ull) & alive;
                while (conf) {
                    int i = (int)__builtin_ctzll(conf);
                    bool deadI = (lane == i) && ((m & alive) != 0ull);
                    u64 d = __ballot(deadI);
                    alive &= ~d; conf &= ~(d | (1ull << i));
                }
                int rank = (int)__popcll(alive & ((1ull << lane) - 1ull));
                int slot = kc0 + rank;
                if (((alive >> lane) & 1ull) && slot < MAXDET) {
                    s_kx1[slot] = x1; s_ky1[slot] = y1; s_kx2[slot] = x2; s_ky2[slot] = y2;
                    s_karea[slot] = area; s_kscore[slot] = sscore; s_ksel[slot] = sidx;
                }
                if (lane == 0) s_alive0 = alive;
            }
            u64 m_low = 0ull, m_high = 0ull;
            bool cand1 = have;
            if (wid == 1) {
                for (int k = 0; k < kc0; ++k) {
                    float iou = iou_fn(x1, y1, x2, y2, area,
                                       s_kx1[k], s_ky1[k], s_kx2[k], s_ky2[k], s_karea[k]);
                    cand1 = cand1 && !(iou > NMS_T);
                }
#pragma unroll 4
                for (int j = 0; j < 64; ++j) {
                    float iou = iou_fn(x1, y1, x2, y2, area,
                                       s_bx1[j], s_by1[j], s_bx2[j], s_by2[j], s_bar[j]);
                    if (iou > NMS_T) m_low |= (1ull << j);
                }
#pragma unroll 4
                for (int j = 0; j < 64; ++j) {
                    float iou = iou_fn(x1, y1, x2, y2, area,
                                       s_bx1[64 + j], s_by1[64 + j], s_bx2[64 + j], s_by2[64 + j], s_bar[64 + j]);
                    if ((iou > NMS_T) && (j < lane)) m_high |= (1ull << j);
                }
            }
            __syncthreads();
            if (wid == 1) {
                u64 alive0 = s_alive0;
                int popc0 = (int)__popcll(alive0);
                bool cand = cand1 && ((m_low & alive0) == 0ull);
                u64 alive = __ballot(cand);
                u64 conf = __ballot((m_high & alive) != 0ull) & alive;
                while (conf) {
                    int i = (int)__builtin_ctzll(conf);
                    bool deadI = (lane == i) && ((m_high & alive) != 0ull);
                    u64 d = __ballot(deadI);
                    alive &= ~d; conf &= ~(d | (1ull << i));
                }
                int rank = (int)__popcll(alive & ((1ull << lane) - 1ull));
                int slot = kc0 + popc0 + rank;
                if (((alive >> lane) & 1ull) && slot < MAXDET) {
                    s_kx1[slot] = x1; s_ky1[slot] = y1; s_kx2[slot] = x2; s_ky2[slot] = y2;
                    s_karea[slot] = area; s_kscore[slot] = sscore; s_ksel[slot] = sidx;
                }
                if (lane == 0) {
                    int nk = kc0 + popc0 + (int)__popcll(alive);
                    s_kc = nk > MAXDET ? MAXDET : nk;
                }
            }
            __syncthreads();
        }
    };

    const unsigned cnt = *cntG;
    if (tid == 0) { s_kc = 0; s_cnt = 0; }
    int U1 = (cnt > CAP) ? 256 : 255;   // exclusive band bound for any fallback continuation
    int U2 = 0;

    // ---- FAST PATH: top-bin candidate list from kernel 1 ----
    if (cnt > 0u && cnt <= CAP) {
        const int sc = (int)cnt;
        for (int t = tid; t < sc; t += BT2) { s_sel[t] = kidxG[t]; s_cb[t] = fb0G[t]; }
        __syncthreads();
        for (int t = tid; t < sc; t += BT2) {
            u64 mine = s_sel[t];
            int rank = 0;
            for (int j = 0; j < sc; ++j) rank += (s_sel[j] > mine) ? 1 : 0;
            s_srt[rank] = mine; s_srtpos[rank] = (unsigned short)t;
        }
        __syncthreads();
        nms_groups(sc);
    }
    __syncthreads();

    // ---- FALLBACK (rare/adversarial): banded selection over all keys ----
    if (s_kc < MAXDET) {
        {
            const uint4* kp = reinterpret_cast<const uint4*>(keysG);
            uint4* sk = reinterpret_cast<uint4*>(s_key);
#pragma unroll
            for (int j = 0; j < NBOX / 4 / BT2; ++j) sk[tid + j * BT2] = kp[tid + j * BT2];
        }
        s_hist[tid] = 0u;
        if (tid == 0) s_cnt = 0;
        __syncthreads();
        for (int j = 0; j < NBOX / BT2; ++j) {
            unsigned k = s_key[tid + j * BT2];
            if (k) {
                int b1, b2; bins_of(k, b1, b2);
                if (b1 < U1 || (b1 == U1 && b2 < U2)) atomicAdd(&s_hist[b1], 1u);
            }
        }
        while (true) {
            __syncthreads();
            if (wid == 0) {
                unsigned c0 = s_hist[lane * 4 + 0], c1s = s_hist[lane * 4 + 1];
                unsigned c2 = s_hist[lane * 4 + 2], c3 = s_hist[lane * 4 + 3];
                unsigned t3 = c3, t2 = c2 + t3, t1 = c1s + t2, t0 = c0 + t1;
                unsigned acc = t0;
#pragma unroll
                for (int d = 1; d < 64; d <<= 1) {
                    unsigned o = __shfl_down(acc, d);
                    if (lane + d < 64) acc += o;
                }
                unsigned excl = acc - t0;
                unsigned totalRem = __shfl(acc, 0);
                if (lane == 0) s_state = (totalRem == 0u) ? 2 : 0;
                if (totalRem != 0u) {
                    unsigned Kt = totalRem < (unsigned)KTGT ? totalRem : (unsigned)KTGT;
                    unsigned incq[4] = { excl + t0, excl + t1, excl + t2, excl + t3 };
                    unsigned abvq[4] = { excl + t1, excl + t2, excl + t3, excl };
#pragma unroll
                    for (int q = 0; q < 4; ++q) {
                        if (incq[q] >= Kt && abvq[q] < Kt) {
                            s_B1 = lane * 4 + q; s_B2 = 0;
                            if (incq[q] > CAP) { s_state = 1; s_refKrem = (int)(Kt - abvq[q]); }
                        }
                    }
                }
            }
            __syncthreads();
            const int st = s_state;
            if (st == 2) break;
            const int B1 = s_B1;
            if (st == 1) {
                s_hist[tid] = 0u;
                __syncthreads();
                for (int j = 0; j < NBOX / BT2; ++j) {
                    unsigned k = s_key[tid + j * BT2];
                    if (k) {
                        int b1, b2; bins_of(k, b1, b2);
                        if ((b1 < U1 || (b1 == U1 && b2 < U2)) && b1 == B1)
                            atomicAdd(&s_hist[b2], 1u);
                    }
                }
                __syncthreads();
                if (wid == 0) {
                    unsigned c0 = s_hist[lane * 4 + 0], c1s = s_hist[lane * 4 + 1];
                    unsigned c2 = s_hist[lane * 4 + 2], c3 = s_hist[lane * 4 + 3];
                    unsigned t3 = c3, t2 = c2 + t3, t1 = c1s + t2, t0 = c0 + t1;
                    unsigned acc = t0;
#pragma unroll
                    for (int d = 1; d < 64; d <<= 1) {
                        unsigned o = __shfl_down(acc, d);
                        if (lane + d < 64) acc += o;
                    }
                    unsigned excl = acc - t0;
                    unsigned Krem = (unsigned)s_refKrem;
                    unsigned incq[4] = { excl + t0, excl + t1, excl + t2, excl + t3 };
                    unsigned abvq[4] = { excl + t1, excl + t2, excl + t3, excl };
#pragma unroll
                    for (int q = 0; q < 4; ++q)
                        if (incq[q] >= Krem && abvq[q] < Krem) s_B2 = lane * 4 + q;
                }
                __syncthreads();
            }
            const int B2 = s_B2;
            for (int j = 0; j < NBOX / BT2; ++j) {
                int i = tid + j * BT2;
                unsigned k = s_key[i];
                if (k) {
                    int b1, b2; bins_of(k, b1, b2);
                    bool inr = (b1 < U1) || (b1 == U1 && b2 < U2);
                    bool sel = inr && ((b1 > B1) || (b1 == B1 && b2 >= B2));
                    if (sel) {
                        int pos = atomicAdd(&s_cnt, 1);
                        if (pos < CAP)
                            s_sel[pos] = (((u64)k) << 13) | (unsigned)(NBOX - 1 - i);
                    }
                }
            }
            __syncthreads();
            const int sc2 = s_cnt < CAP ? s_cnt : CAP;
            for (int t = tid; t < sc2; t += BT2) {
                u64 mine = s_sel[t];
                int bidx = NBOX - 1 - (int)(mine & 8191ull);
                s_cb[t] = *reinterpret_cast<const float4*>(boxes + bidx * 12);
                int rank = 0;
                for (int j = 0; j < sc2; ++j) rank += (s_sel[j] > mine) ? 1 : 0;
                s_srt[rank] = mine; s_srtpos[rank] = (unsigned short)t;
            }
            __syncthreads();
            nms_groups(sc2);
            if (s_kc >= MAXDET) break;
            U1 = B1; U2 = B2;
            s_hist[tid] = 0u;
            if (tid == 0) s_cnt = 0;
            __syncthreads();
            for (int j = 0; j < NBOX / BT2; ++j) {
                unsigned k = s_key[tid + j * BT2];
                if (k) {
                    int b1, b2; bins_of(k, b1, b2);
                    if (b1 < U1 || (b1 == U1 && b2 < U2)) atomicAdd(&s_hist[b1], 1u);
                }
            }
        }
    }
    __syncthreads();

    // ---- output: 100 slots ----
    if (tid < MAXDET) {
        const int kc = s_kc;
        float* ob = out;                 // (100,12)
        float* od = out + MAXDET * 12;   // (100,3)
        float* os = out + MAXDET * 15;   // (100,)
        float* ol = out + MAXDET * 16;   // (100,) labels
        float* oo = out + MAXDET * 17;   // (100,) orient
        float4* obr = reinterpret_cast<float4*>(ob + tid * 12);
        if (tid < kc) {
            int sel = s_ksel[tid];
            const float4* br = reinterpret_cast<const float4*>(boxes + sel * 12);
            obr[0] = br[0]; obr[1] = br[1]; obr[2] = br[2];
            od[tid * 3 + 0] = dims[sel * 3 + 0];
            od[tid * 3 + 1] = dims[sel * 3 + 1];
            od[tid * 3 + 2] = dims[sel * 3 + 2];
            os[tid] = s_kscore[tid];
            ol[tid] = 0.0f;
            const float4 c0 = *reinterpret_cast<const float4*>(cls + sel * 8);
            const float4 c1 = *reinterpret_cast<const float4*>(cls + sel * 8 + 4);
            float m0 = fmaxf(c0.x, c1.x);
            float m1 = fmaxf(c0.y, c1.y);
            float m2 = fmaxf(c0.z, c1.z);
            float m3 = fmaxf(c0.w, c1.w);
            int o = 0; float best = m0;
            if (m1 > best) { best = m1; o = 1; }
            if (m2 > best) { best = m2; o = 2; }
            if (m3 > best) { best = m3; o = 3; }
            oo[tid] = (float)o;
        } else {
            const float4 neg1 = make_float4(-1.f, -1.f, -1.f, -1.f);
            obr[0] = neg1; obr[1] = neg1; obr[2] = neg1;
            od[tid * 3 + 0] = -1.0f; od[tid * 3 + 1] = -1.0f; od[tid * 3 + 2] = -1.0f;
            os[tid] = -1.0f; ol[tid] = -1.0f; oo[tid] = -1.0f;
        }
    }
}

extern "C" void kernel_launch(void* const* d_in, const int* in_sizes, int n_in,
                              void* d_out, int out_size, void* d_ws, size_t ws_size,
                              hipStream_t stream) {
    const float* boxes = (const float*)d_in[0];
    const float* dims  = (const float*)d_in[1];
    const float* cls   = (const float*)d_in[2];
    float* out = (float*)d_out;
    unsigned char* ws = (unsigned char*)d_ws;
    unsigned* cnt  = (unsigned*)(ws);
    unsigned* keys = (unsigned*)(ws + WS_KEYS);
    u64* kidx      = (u64*)(ws + WS_KIDX);
    float4* fb0    = (float4*)(ws + WS_FB0);
    (void)in_sizes; (void)n_in; (void)out_size; (void)ws_size;
    hipMemsetAsync(cnt, 0, sizeof(unsigned), stream);
    score_push_kernel<<<NBOX / 128, 128, 0, stream>>>(boxes, cls, keys, cnt, kidx, fb0);
    select_nms_kernel<<<1, BT2, 0, stream>>>(boxes, dims, cls, keys, cnt, kidx, fb0, out);
}

// Round 7
// 27.012 us; speedup vs baseline: 1.2444x; 1.1731x over previous
//
#include <hip/hip_runtime.h>

#define NBOX 8192
#define BT 1024
#define MAXDET 100
#define SCORE_T 0.05f
#define NMS_T 0.5f
#define CAP 1024
#define KTGT 128
#define TOPBIN_T 0.99609375f   // 255/256: top value-uniform bin

typedef unsigned long long u64;

__device__ __forceinline__ float rl_f(float v, int j) {
    return __int_as_float(__builtin_amdgcn_readlane(__float_as_int(v), j));
}

__device__ __forceinline__ float iou_fn(float x1, float y1, float x2, float y2, float area,
                                        float bx1, float by1, float bx2, float by2, float barea) {
    float iw = fminf(x2, bx2) - fmaxf(x1, bx1);
    float ih = fminf(y2, by2) - fmaxf(y1, by1);
    iw = fmaxf(iw, 0.0f);
    ih = fmaxf(ih, 0.0f);
    float inter = iw * ih;
    return inter / fmaxf(area + barea - inter, 1e-8f);
}

__device__ __forceinline__ void bins_of(unsigned k, int& b1, int& b2) {
    float s = __uint_as_float(k & 0x7FFFFFFFu);
    b1 = (int)(s * 256.0f); if (b1 > 255) b1 = 255;
    b2 = (int)(s * 65536.0f) & 255;
}

__global__ __launch_bounds__(BT) void filterdet_kernel(
    const float* __restrict__ boxes, const float* __restrict__ dims,
    const float* __restrict__ cls, float* __restrict__ out) {
    __shared__ unsigned s_key[NBOX];              // 32KB
    __shared__ unsigned s_hist[256];
    __shared__ u64 s_sel[CAP];                    // 8KB
    __shared__ u64 s_srt[CAP];                    // 8KB
    __shared__ unsigned short s_srtpos[CAP];      // 2KB
    __shared__ float4 s_cb[CAP];                  // 16KB
    __shared__ float4 s_bb[128];
    __shared__ float s_bar[128];
    __shared__ float4 s_kb[MAXDET];
    __shared__ float s_karea[MAXDET], s_kscore[MAXDET];
    __shared__ int s_ksel[MAXDET];
    __shared__ int s_kc, s_cnt, s_B1, s_B2, s_state, s_refKrem;
    __shared__ u64 s_alive0;

    const int tid = threadIdx.x;
    const int lane = tid & 63;
    const int wid = tid >> 6;

    // rank-sort s_sel[0..sc) desc (keys distinct); 8-deep independent LDS reads
    auto rank_scatter = [&](int sc, bool loadBox) {
        if (tid < sc) {
            u64 mine = s_sel[tid];
            float4 pb = make_float4(0.f, 0.f, 0.f, 0.f);
            if (loadBox) {
                int bidx = NBOX - 1 - (int)(mine & 8191ull);
                pb = *reinterpret_cast<const float4*>(boxes + bidx * 12);
            }
            int rank = 0;
            int j = 0;
            for (; j + 8 <= sc; j += 8) {
                u64 a0 = s_sel[j + 0], a1 = s_sel[j + 1], a2 = s_sel[j + 2], a3 = s_sel[j + 3];
                u64 a4 = s_sel[j + 4], a5 = s_sel[j + 5], a6 = s_sel[j + 6], a7 = s_sel[j + 7];
                rank += (int)(a0 > mine) + (int)(a1 > mine) + (int)(a2 > mine) + (int)(a3 > mine)
                      + (int)(a4 > mine) + (int)(a5 > mine) + (int)(a6 > mine) + (int)(a7 > mine);
            }
            for (; j < sc; ++j) rank += (s_sel[j] > mine) ? 1 : 0;
            s_srt[rank] = mine;
            s_srtpos[rank] = (unsigned short)tid;
            if (loadBox) s_cb[tid] = pb;
        }
    };

    // exact greedy NMS over s_srt[0..scN), 2-wave cooperative, groups of 128
    auto nms_groups = [&](int scN) {
        for (int base = 0; base < scN && s_kc < MAXDET; base += 128) {
            const int kc0 = s_kc;
            float x1 = 0.f, y1 = 0.f, x2 = 0.f, y2 = 0.f, area = 0.f, sscore = 0.f;
            int sidx = 0; bool have = false;
            if (wid < 2) {
                int p = base + wid * 64 + lane;
                have = p < scN;
                u64 v = have ? s_srt[p] : 0ull;
                int cp = have ? (int)s_srtpos[p] : 0;
                sidx = NBOX - 1 - (int)(v & 8191ull);
                sscore = __uint_as_float(((unsigned)(v >> 13)) & 0x7FFFFFFFu);
                float4 b = s_cb[cp];
                if (have) { x1 = b.x; y1 = b.y; x2 = b.z; y2 = b.w; area = (x2 - x1) * (y2 - y1); }
                int sl = wid * 64 + lane;
                s_bb[sl] = make_float4(x1, y1, x2, y2); s_bar[sl] = area;
            }
            __syncthreads();
            if (wid == 0) {
                bool cand = have;
                for (int k = 0; k < kc0; ++k) {
                    float4 kb = s_kb[k];
                    float iou = iou_fn(x1, y1, x2, y2, area, kb.x, kb.y, kb.z, kb.w, s_karea[k]);
                    cand = cand && !(iou > NMS_T);
                }
                u64 m = 0ull;
#pragma unroll 8
                for (int j = 0; j < 64; ++j) {
                    float iou = iou_fn(x1, y1, x2, y2, area,
                                       rl_f(x1, j), rl_f(y1, j), rl_f(x2, j), rl_f(y2, j), rl_f(area, j));
                    if ((iou > NMS_T) && (j < lane)) m |= (1ull << j);
                }
                u64 alive = __ballot(cand);
                u64 conf = __ballot((m & alive) != 0ull) & alive;
                while (conf) {
                    int i = (int)__builtin_ctzll(conf);
                    bool deadI = (lane == i) && ((m & alive) != 0ull);
                    u64 d = __ballot(deadI);
                    alive &= ~d; conf &= ~(d | (1ull << i));
                }
                int rank = (int)__popcll(alive & ((1ull << lane) - 1ull));
                int slot = kc0 + rank;
                if (((alive >> lane) & 1ull) && slot < MAXDET) {
                    s_kb[slot] = make_float4(x1, y1, x2, y2);
                    s_karea[slot] = area; s_kscore[slot] = sscore; s_ksel[slot] = sidx;
                }
                if (lane == 0) s_alive0 = alive;
            }
            u64 m_low = 0ull, m_high = 0ull;
            bool cand1 = have;
            if (wid == 1) {
                for (int k = 0; k < kc0; ++k) {
                    float4 kb = s_kb[k];
                    float iou = iou_fn(x1, y1, x2, y2, area, kb.x, kb.y, kb.z, kb.w, s_karea[k]);
                    cand1 = cand1 && !(iou > NMS_T);
                }
#pragma unroll 8
                for (int j = 0; j < 64; ++j) {
                    float4 bb = s_bb[j];
                    float iou = iou_fn(x1, y1, x2, y2, area, bb.x, bb.y, bb.z, bb.w, s_bar[j]);
                    if (iou > NMS_T) m_low |= (1ull << j);
                }
#pragma unroll 8
                for (int j = 0; j < 64; ++j) {
                    float iou = iou_fn(x1, y1, x2, y2, area,
                                       rl_f(x1, j), rl_f(y1, j), rl_f(x2, j), rl_f(y2, j), rl_f(area, j));
                    if ((iou > NMS_T) && (j < lane)) m_high |= (1ull << j);
                }
            }
            __syncthreads();
            if (wid == 1) {
                u64 alive0 = s_alive0;
                int popc0 = (int)__popcll(alive0);
                bool cand = cand1 && ((m_low & alive0) == 0ull);
                u64 alive = __ballot(cand);
                u64 conf = __ballot((m_high & alive) != 0ull) & alive;
                while (conf) {
                    int i = (int)__builtin_ctzll(conf);
                    bool deadI = (lane == i) && ((m_high & alive) != 0ull);
                    u64 d = __ballot(deadI);
                    alive &= ~d; conf &= ~(d | (1ull << i));
                }
                int rank = (int)__popcll(alive & ((1ull << lane) - 1ull));
                int slot = kc0 + popc0 + rank;
                if (((alive >> lane) & 1ull) && slot < MAXDET) {
                    s_kb[slot] = make_float4(x1, y1, x2, y2);
                    s_karea[slot] = area; s_kscore[slot] = sscore; s_ksel[slot] = sidx;
                }
                if (lane == 0) {
                    int nk = kc0 + popc0 + (int)__popcll(alive);
                    s_kc = nk > MAXDET ? MAXDET : nk;
                }
            }
            __syncthreads();
        }
    };

    // ---- Phase 1: keys into regs+LDS; then push top-bin candidates via LDS atomics ----
    unsigned keyr[8];
#pragma unroll
    for (int j = 0; j < 8; ++j) {
        int i = tid + j * BT;
        const float4 c0 = *reinterpret_cast<const float4*>(cls + i * 8);
        const float4 c1 = *reinterpret_cast<const float4*>(cls + i * 8 + 4);
        float s = fmaxf(fmaxf(fmaxf(c0.x, c1.x), fmaxf(c0.y, c1.y)),
                        fmaxf(fmaxf(c0.z, c1.z), fmaxf(c0.w, c1.w)));
        unsigned u = __float_as_uint(s);
        unsigned key = (u >> 31) ? ~u : (u | 0x80000000u);
        key = (s > SCORE_T) ? key : 0u;
        keyr[j] = key;
        s_key[i] = key;
    }
    if (tid == 0) { s_kc = 0; s_cnt = 0; }
    __syncthreads();
#pragma unroll
    for (int j = 0; j < 8; ++j) {
        unsigned k = keyr[j];
        if (k) {
            float s = __uint_as_float(k & 0x7FFFFFFFu);
            if (s >= TOPBIN_T) {
                int pos = atomicAdd(&s_cnt, 1);
                if (pos < CAP) {
                    int i = tid + j * BT;
                    s_sel[pos] = (((u64)k) << 13) | (unsigned)(NBOX - 1 - i);
                    s_cb[pos] = *reinterpret_cast<const float4*>(boxes + i * 12);
                }
            }
        }
    }
    __syncthreads();
    const int cnt0 = s_cnt;
    const bool ovf = cnt0 > CAP;

    // ---- FAST PATH: NMS over the top-bin prefix ----
    if (!ovf && cnt0 > 0) {
        rank_scatter(cnt0, false);
        __syncthreads();
        nms_groups(cnt0);
    }

    int U1 = ovf ? 256 : 255;   // exclusive band bound for fallback continuation
    int U2 = 0;

    // ---- FALLBACK (rare/adversarial): banded selection over all keys ----
    if (s_kc < MAXDET) {
        if (tid < 256) s_hist[tid] = 0u;
        if (tid == 0) s_cnt = 0;
        __syncthreads();
        for (int j = 0; j < NBOX / BT; ++j) {
            unsigned k = s_key[tid + j * BT];
            if (k) {
                int b1, b2; bins_of(k, b1, b2);
                if (b1 < U1 || (b1 == U1 && b2 < U2)) atomicAdd(&s_hist[b1], 1u);
            }
        }
        while (true) {
            __syncthreads();
            if (wid == 0) {
                unsigned c0 = s_hist[lane * 4 + 0], c1s = s_hist[lane * 4 + 1];
                unsigned c2 = s_hist[lane * 4 + 2], c3 = s_hist[lane * 4 + 3];
                unsigned t3 = c3, t2 = c2 + t3, t1 = c1s + t2, t0 = c0 + t1;
                unsigned acc = t0;
#pragma unroll
                for (int d = 1; d < 64; d <<= 1) {
                    unsigned o = __shfl_down(acc, d);
                    if (lane + d < 64) acc += o;
                }
                unsigned excl = acc - t0;
                unsigned totalRem = __shfl(acc, 0);
                if (lane == 0) s_state = (totalRem == 0u) ? 2 : 0;
                if (totalRem != 0u) {
                    unsigned Kt = totalRem < (unsigned)KTGT ? totalRem : (unsigned)KTGT;
                    unsigned incq[4] = { excl + t0, excl + t1, excl + t2, excl + t3 };
                    unsigned abvq[4] = { excl + t1, excl + t2, excl + t3, excl };
#pragma unroll
                    for (int q = 0; q < 4; ++q) {
                        if (incq[q] >= Kt && abvq[q] < Kt) {
                            s_B1 = lane * 4 + q; s_B2 = 0;
                            if (incq[q] > CAP) { s_state = 1; s_refKrem = (int)(Kt - abvq[q]); }
                        }
                    }
                }
            }
            __syncthreads();
            const int st = s_state;
            if (st == 2) break;
            const int B1 = s_B1;
            if (st == 1) {
                if (tid < 256) s_hist[tid] = 0u;
                __syncthreads();
                for (int j = 0; j < NBOX / BT; ++j) {
                    unsigned k = s_key[tid + j * BT];
                    if (k) {
                        int b1, b2; bins_of(k, b1, b2);
                        if ((b1 < U1 || (b1 == U1 && b2 < U2)) && b1 == B1)
                            atomicAdd(&s_hist[b2], 1u);
                    }
                }
                __syncthreads();
                if (wid == 0) {
                    unsigned c0 = s_hist[lane * 4 + 0], c1s = s_hist[lane * 4 + 1];
                    unsigned c2 = s_hist[lane * 4 + 2], c3 = s_hist[lane * 4 + 3];
                    unsigned t3 = c3, t2 = c2 + t3, t1 = c1s + t2, t0 = c0 + t1;
                    unsigned acc = t0;
#pragma unroll
                    for (int d = 1; d < 64; d <<= 1) {
                        unsigned o = __shfl_down(acc, d);
                        if (lane + d < 64) acc += o;
                    }
                    unsigned excl = acc - t0;
                    unsigned Krem = (unsigned)s_refKrem;
                    unsigned incq[4] = { excl + t0, excl + t1, excl + t2, excl + t3 };
                    unsigned abvq[4] = { excl + t1, excl + t2, excl + t3, excl };
#pragma unroll
                    for (int q = 0; q < 4; ++q)
                        if (incq[q] >= Krem && abvq[q] < Krem) s_B2 = lane * 4 + q;
                }
                __syncthreads();
            }
            const int B2 = s_B2;
            for (int j = 0; j < NBOX / BT; ++j) {
                int i = tid + j * BT;
                unsigned k = s_key[i];
                if (k) {
                    int b1, b2; bins_of(k, b1, b2);
                    bool inr = (b1 < U1) || (b1 == U1 && b2 < U2);
                    bool sel = inr && ((b1 > B1) || (b1 == B1 && b2 >= B2));
                    if (sel) {
                        int pos = atomicAdd(&s_cnt, 1);
                        if (pos < CAP)
                            s_sel[pos] = (((u64)k) << 13) | (unsigned)(NBOX - 1 - i);
                    }
                }
            }
            __syncthreads();
            const int sc2 = s_cnt < CAP ? s_cnt : CAP;
            rank_scatter(sc2, true);
            __syncthreads();
            nms_groups(sc2);
            if (s_kc >= MAXDET) break;
            U1 = B1; U2 = B2;
            if (tid < 256) s_hist[tid] = 0u;
            if (tid == 0) s_cnt = 0;
            __syncthreads();
            for (int j = 0; j < NBOX / BT; ++j) {
                unsigned k = s_key[tid + j * BT];
                if (k) {
                    int b1, b2; bins_of(k, b1, b2);
                    if (b1 < U1 || (b1 == U1 && b2 < U2)) atomicAdd(&s_hist[b1], 1u);
                }
            }
        }
    }
    __syncthreads();

    // ---- output: 100 slots ----
    if (tid < MAXDET) {
        const int kc = s_kc;
        float* ob = out;                 // (100,12)
        float* od = out + MAXDET * 12;   // (100,3)
        float* os = out + MAXDET * 15;   // (100,)
        float* ol = out + MAXDET * 16;   // (100,) labels
        float* oo = out + MAXDET * 17;   // (100,) orient
        float4* obr = reinterpret_cast<float4*>(ob + tid * 12);
        if (tid < kc) {
            int sel = s_ksel[tid];
            const float4* br = reinterpret_cast<const float4*>(boxes + sel * 12);
            obr[0] = br[0]; obr[1] = br[1]; obr[2] = br[2];
            od[tid * 3 + 0] = dims[sel * 3 + 0];
            od[tid * 3 + 1] = dims[sel * 3 + 1];
            od[tid * 3 + 2] = dims[sel * 3 + 2];
            os[tid] = s_kscore[tid];
            ol[tid] = 0.0f;
            const float4 c0 = *reinterpret_cast<const float4*>(cls + sel * 8);
            const float4 c1 = *reinterpret_cast<const float4*>(cls + sel * 8 + 4);
            float m0 = fmaxf(c0.x, c1.x);
            float m1 = fmaxf(c0.y, c1.y);
            float m2 = fmaxf(c0.z, c1.z);
            float m3 = fmaxf(c0.w, c1.w);
            int o = 0; float best = m0;
            if (m1 > best) { best = m1; o = 1; }
            if (m2 > best) { best = m2; o = 2; }
            if (m3 > best) { best = m3; o = 3; }
            oo[tid] = (float)o;
        } else {
            const float4 neg1 = make_float4(-1.f, -1.f, -1.f, -1.f);
            obr[0] = neg1; obr[1] = neg1; obr[2] = neg1;
            od[tid * 3 + 0] = -1.0f; od[tid * 3 + 1] = -1.0f; od[tid * 3 + 2] = -1.0f;
            os[tid] = -1.0f; ol[tid] = -1.0f; oo[tid] = -1.0f;
        }
    }
}

extern "C" void kernel_launch(void* const* d_in, const int* in_sizes, int n_in,
                              void* d_out, int out_size, void* d_ws, size_t ws_size,
                              hipStream_t stream) {
    const float* boxes = (const float*)d_in[0];
    const float* dims  = (const float*)d_in[1];
    const float* cls   = (const float*)d_in[2];
    float* out = (float*)d_out;
    (void)in_sizes; (void)n_in; (void)out_size; (void)d_ws; (void)ws_size;
    filterdet_kernel<<<1, BT, 0, stream>>>(boxes, dims, cls, out);
}